// Round 1
// 118.477 us; speedup vs baseline: 1.0065x; 1.0065x over previous
//
#include <hip/hip_runtime.h>
#include <hip/hip_fp16.h>

// Problem constants (match reference)
#define BB 8
#define CC 128
#define HH 112
#define WW 112
#define NTH 224            // 16 row-groups x 14 col-groups
#define RG 7               // output rows per thread (16*7 = 112 = full plane)

// LUT depthwise 3x3, stride 1, pad 1:
//   t1 = clip(round(w*1000)), t2 = clip(round(x_pad)), both [-255,255]
//   out = sum_taps sign(t1,t2)*lut[|t1|,|t2|] / 1000 (sign=+1 iff strictly same sign)
//
// R6 (LDS-gather-bound per R5 analysis: 357 ds_read_b32/thread was the pipe):
//  - ONE 9-tap record per quantized value idx = t2+255:
//      Big[idx]  = k0..k7 as 8 x fp16  (16 B -> one ds_read_b128)
//      Tail[idx] = k8     as f32       ( 4 B -> one ds_read_b32; f32 keeps
//                                        absmax near the R5 level)
//  - Each input pixel is quantized once and gathered ONCE (2 reads), then
//    scatter-accumulated into a rolling ring of 3 pending output rows
//    (9 fma_mix per interior pixel). 180 ds_reads/thread vs 357 (-50%),
//    FMA count unchanged (504 = 9/output), off[3][10] ring eliminated.
__device__ __forceinline__ unsigned pkh2(float a, float b) {
    __half2 h = __halves2half2(__float2half_rn(a), __float2half_rn(b));
    return *reinterpret_cast<unsigned*>(&h);
}

__global__ __launch_bounds__(NTH, 4)
void approx_dconv_kernel(const float* __restrict__ x,
                         const float* __restrict__ w,
                         const float* __restrict__ lut,
                         float* __restrict__ out) {
    __shared__ uint4 Big[512];    // taps k0..k7, 8 x fp16 per entry
    __shared__ float Tail[512];   // tap  k8, f32 per entry

    const int tid = threadIdx.x;
    const int bc  = blockIdx.x;   // b*CC + c
    const int c   = bc % CC;

    // ---- 1) build signed 9-tap records (mirror fill) ---------------------
    const float* wc = w + c * 9;
    int  i1[9];
    bool sp[9], sn[9];
    #pragma unroll
    for (int k = 0; k < 9; ++k) {
        float t1 = rintf(wc[k] * 1000.0f);
        t1 = fminf(fmaxf(t1, -255.0f), 255.0f);
        i1[k] = (int)fabsf(t1);
        sp[k] = (t1 > 0.0f);
        sn[k] = (t1 < 0.0f);
    }
    for (int i = tid; i < 256; i += NTH) {       // i == |t2|
        float pv[9], nv[9];
        #pragma unroll
        for (int k = 0; k < 9; ++k) {
            const float v = lut[i1[k] * 256 + i];
            pv[k] = (sp[k] && i > 0) ? v : -v;   // t2 = +i
            nv[k] = (sn[k] && i > 0) ? v : -v;   // t2 = -i
        }
        uint4 bp, bn;
        bp.x = pkh2(pv[0], pv[1]); bp.y = pkh2(pv[2], pv[3]);
        bp.z = pkh2(pv[4], pv[5]); bp.w = pkh2(pv[6], pv[7]);
        bn.x = pkh2(nv[0], nv[1]); bn.y = pkh2(nv[2], nv[3]);
        bn.z = pkh2(nv[4], nv[5]); bn.w = pkh2(nv[6], nv[7]);
        Big[255 + i] = bp;  Tail[255 + i] = pv[8];
        Big[255 - i] = bn;  Tail[255 - i] = nv[8];
    }
    __syncthreads();

    // ---- 2) compute: gather-once, scatter into 3-row acc ring ------------
    const int rg = tid / 14;                     // 0..15
    const int cg = tid % 14;                     // 0..13
    const int y0 = rg * RG;
    const int c0 = cg * 8;
    const float* xp = x + (size_t)bc * (HH * WW);
    float* op = out + (size_t)bc * (HH * WW);

    const char* Bb = (const char*)Big;
    const char* Tb = (const char*)Tail;
    const float cm = 0.001f;

    float acc[3][8];
    #pragma unroll
    for (int s2 = 0; s2 < 3; ++s2)
        #pragma unroll
        for (int j = 0; j < 8; ++j) acc[s2][j] = 0.0f;

    #pragma unroll
    for (int R = -1; R <= RG; ++R) {             // input row y0+R
        // quantize this input row once -> Big byte offsets
        int oB[10];
        const int py = y0 + R;
        if (py >= 0 && py < HH) {
            const float* rp = xp + py * WW + c0;
            float p[10];
            p[0] = (cg > 0) ? rp[-1] : 0.0f;     // left halo / zero pad
            const float4 A  = *(const float4*)rp;
            const float4 Bv = *(const float4*)(rp + 4);
            p[1] = A.x;  p[2] = A.y;  p[3] = A.z;  p[4] = A.w;
            p[5] = Bv.x; p[6] = Bv.y; p[7] = Bv.z; p[8] = Bv.w;
            p[9] = (cg < 13) ? rp[8] : 0.0f;     // right halo / zero pad
            #pragma unroll
            for (int j = 0; j < 10; ++j) {
                const float t = __builtin_amdgcn_fmed3f(rintf(p[j]), -255.0f, 255.0f);
                oB[j] = ((int)t) * 16 + 255 * 16;          // v_lshl_add
            }
        } else {
            #pragma unroll
            for (int j = 0; j < 10; ++j) oB[j] = 255 * 16; // t2 = 0 entry
        }

        #pragma unroll
        for (int px = 0; px < 10; ++px) {        // pixel col = c0-1+px
            const uint4 G  = *(const uint4*)(Bb + oB[px]);
            const float t8 = *(const float*)(Tb + (oB[px] >> 2));
            __half2 hh[4];
            hh[0] = *(const __half2*)&G.x; hh[1] = *(const __half2*)&G.y;
            hh[2] = *(const __half2*)&G.z; hh[3] = *(const __half2*)&G.w;
            #pragma unroll
            for (int r = 0; r < 3; ++r) {
                const int o = R + 1 - r;         // local output row touched
                if (o < 0 || o > 6) continue;    // compile-time after unroll
                float* Ar = acc[(o + 3) % 3];
                #pragma unroll
                for (int s = 0; s < 3; ++s) {
                    const int j = px - s;        // local output col
                    if (j < 0 || j > 7) continue;
                    const int k = r * 3 + s;
                    const float tv = (k == 8) ? t8
                                   : ((k & 1) ? __high2float(hh[k >> 1])
                                              : __low2float (hh[k >> 1]));
                    Ar[j] = fmaf(tv, cm, Ar[j]); // v_fma_mix_f32 for fp16 taps
                }
            }
        }

        if (R >= 1) {                            // retire completed out row R-1
            const int o = R - 1;
            float* Ar = acc[(o + 3) % 3];
            float* od = op + (y0 + o) * WW + c0;
            *(float4*)od       = make_float4(Ar[0], Ar[1], Ar[2], Ar[3]);
            *(float4*)(od + 4) = make_float4(Ar[4], Ar[5], Ar[6], Ar[7]);
            #pragma unroll
            for (int j = 0; j < 8; ++j) Ar[j] = 0.0f;  // slot reused at R+1
        }
    }
}

extern "C" void kernel_launch(void* const* d_in, const int* in_sizes, int n_in,
                              void* d_out, int out_size, void* d_ws, size_t ws_size,
                              hipStream_t stream) {
    const float* x   = (const float*)d_in[0];
    const float* w   = (const float*)d_in[1];
    const float* lut = (const float*)d_in[2];
    float* out = (float*)d_out;
    (void)in_sizes; (void)n_in; (void)out_size; (void)d_ws; (void)ws_size;

    const int grid = BB * CC;                    // 1024 blocks: one (b,c) plane each
    approx_dconv_kernel<<<grid, NTH, 0, stream>>>(x, w, lut, out);
}